// Round 10
// baseline (281.826 us; speedup 1.0000x reference)
//
#include <hip/hip_runtime.h>
#include <cstdint>

// ---------------------------------------------------------------------------
// AttentionSelector: selected = softmax(query @ (x@Wk^T+bk)^T) @ x
// R13: 3-dispatch spine, Part BF16. VERIFIED 259.3 (flash 181.5).
// R15-R19: schedule/hint edits null or negative; permlane hazard found+fixed
//      (s_nop-hardened plswap, R18-verified).
// R20: LDS chunk staging WIN (flash 171.5). R21 desync NULL. R22 hybrid
//      K-global/X-LDS split REGRESSED (189.3) -> pipe-split model dead.
// MODEL (R9, fits all rounds): per-pipe busy over R20's 411.6k cyc/SIMD:
//      matrix 44%, trans 8%, LDS 16%, VALU ~10% -> NOTHING saturated.
//      Flash is DEPENDENCY-bound at 2 waves/SIMD (qt=2 needs o+s = 256
//      unified regs/wave -> register-walled occupancy).
// R23: qt=1. Per-wave state halves (o[3]=48A + s=16 + aQ=20 + transients
//      ~120-140) -> __launch_bounds__(256,4) targets <=128 -> 16 waves/CU,
//      2x latency hiding. Grid 64 qblocks x NS = 1024 (4 blocks/CU). LDS
//      staging: 1-tile chunks {K(t+1), X(t)} double-buffered (22.5KB/block,
//      90KB/CU), R20's verified stage->barrier->consume pattern. Per-wave
//      math = strict subset of verified qt=2 code (f1/s1 half dropped).
// ---------------------------------------------------------------------------

typedef __bf16    bf16x4 __attribute__((ext_vector_type(4)));
typedef __bf16    bf16x8 __attribute__((ext_vector_type(8)));
typedef _Float16  f16x4  __attribute__((ext_vector_type(4)));
typedef _Float16  f16x8  __attribute__((ext_vector_type(8)));
typedef float     f32x2  __attribute__((ext_vector_type(2)));
typedef float     f32x16 __attribute__((ext_vector_type(16)));

extern "C" __device__ float __ocml_native_exp2_f32(float);

#define NUM_PAIRS   65536
#define NUM_Q       8192
#define DIM         66
#define QPITCH      80        // Qh row pitch (f16)
#define KFT         2560      // Af f16 per 32-pair tile (5 kk x 512)
#define XFT         3072      // Xf bf16 per 32-pair tile (6 c x 512)
#define PARTP       68        // partial row pitch (bf16)
#define NS          16
#define NTILES      (NUM_PAIRS/32)   // 2048

#define TILE_K_B    5120                // Af bytes per tile
#define TILE_X_B    6144                // Xf bytes per tile
#define CH_B        (TILE_K_B+TILE_X_B) // 11264 (1-tile chunk: K(t+1), X(t))

__device__ __forceinline__ f32x16 mfma_bf16(bf16x8 a, bf16x8 b, f32x16 c) {
    return __builtin_amdgcn_mfma_f32_32x32x16_bf16(a, b, c, 0, 0, 0);
}
__device__ __forceinline__ f32x16 mfma_f16(f16x8 a, f16x8 b, f32x16 c) {
    return __builtin_amdgcn_mfma_f32_32x32x16_f16(a, b, c, 0, 0, 0);
}
// gfx950: exchange lanes 32..63 of a with lanes 0..31 of b.
// HAZARD-HARDENED (R18, verified): VALU-write -> permlane-read needs wait
// states; compiler can't see inside inline asm, so carry our own s_nop.
__device__ __forceinline__ void plswap(unsigned &a, unsigned &b) {
    asm volatile("s_nop 1\n\t"
                 "v_permlane32_swap_b32 %0, %1\n\t"
                 "s_nop 1"
                 : "+v"(a), "+v"(b));
}
__device__ __forceinline__ unsigned packbf(float a, float b) {
    union { __bf16 h[2]; unsigned u; } t;
    t.h[0] = (__bf16)a; t.h[1] = (__bf16)b;
    return t.u;
}
union U4 { unsigned u[4]; bf16x8 v; };

// async global->LDS, 16B per lane, linear dest (wave base + lane*16)
__device__ __forceinline__ void gload16(const void* g, void* l) {
    __builtin_amdgcn_global_load_lds(
        (const __attribute__((address_space(1))) unsigned int*)g,
        (__attribute__((address_space(3))) unsigned int*)l,
        16, 0, 0);
}

// Sᵀ C-tile (col=query l31, row(pair)=(r&3)+8*(r>>2)+4h) -> exp2 -> two PV
// A-frags (par0: pairs 0..15, par1: 16..31) via permlane32_swap (verified).
__device__ __forceinline__ void makefrags(const f32x16 &s, U4 *f) {
    float P[16];
    #pragma unroll
    for (int r = 0; r < 16; ++r) P[r] = __ocml_native_exp2_f32(s[r]);
    unsigned E0 = packbf(P[0],  P[1]),  E1 = packbf(P[2],  P[3]);
    unsigned F0 = packbf(P[4],  P[5]),  F1 = packbf(P[6],  P[7]);
    plswap(E0, F0); plswap(E1, F1);
    f[0].u[0] = E0; f[0].u[1] = E1; f[0].u[2] = F0; f[0].u[3] = F1;
    unsigned G0 = packbf(P[8],  P[9]),  G1 = packbf(P[10], P[11]);
    unsigned H0 = packbf(P[12], P[13]), H1 = packbf(P[14], P[15]);
    plswap(G0, H0); plswap(G1, H1);
    f[1].u[0] = G0; f[1].u[1] = G1; f[1].u[2] = H0; f[1].u[3] = H1;
}

// ---------------------------------------------------------------------------
// Prep: blocks 0..511 -> 128 pairs each: x -> Af (f16 S-frags) + Xf (bf16 PV
//       frags, ones-trick for row 66). blocks 512..575 -> 128 queries each:
//       Qh = (Wk^T q)*log2e via mfma f16.   (unchanged, verified)
// ---------------------------------------------------------------------------
#define PAP 104   // LDS pitch (f16)
__global__ __launch_bounds__(256) void prep_kernel(
    const float* __restrict__ x, const float* __restrict__ query,
    const float* __restrict__ Wk,
    unsigned short* __restrict__ Af_u, unsigned short* __restrict__ Xf_u,
    unsigned short* __restrict__ Qh_u) {
    const int tid = threadIdx.x;
    const int lane = tid & 63, w = tid >> 6;
    const int l31 = lane & 31, h = lane >> 5;

    if (blockIdx.x >= 512) {
        // ---- query side: Qh = (Wk^T q) * log2e via mfma ----
        __shared__ _Float16 sq[128 * PAP];    // query rows f16, pads 0
        __shared__ _Float16 sWT[96 * PAP];    // sWT[e][d] = Wk[d][e]*log2e, pads 0
        _Float16* Qh = (_Float16*)Qh_u;
        const long q0 = (long)(blockIdx.x - 512) * 128;

        for (int i = tid; i < 128 * PAP / 2; i += 256) ((unsigned*)sq)[i] = 0u;
        for (int i = tid; i < 96 * PAP / 2; i += 256)  ((unsigned*)sWT)[i] = 0u;
        __syncthreads();

        for (int i = tid; i < 128 * 33; i += 256) {       // f32x2 loads
            int r = i / 33, c2 = (i % 33) * 2;
            f32x2 v = *(const f32x2*)&query[(q0 + r) * DIM + c2];
            sq[r * PAP + c2]     = (_Float16)v.x;
            sq[r * PAP + c2 + 1] = (_Float16)v.y;
        }
        for (int i = tid; i < DIM * 33; i += 256) {       // Wk transposed, scaled
            int d = i / 33, e2 = (i % 33) * 2;
            f32x2 v = *(const f32x2*)&Wk[d * DIM + e2];
            sWT[e2 * PAP + d]       = (_Float16)(v.x * 1.4426950408889634f);
            sWT[(e2 + 1) * PAP + d] = (_Float16)(v.y * 1.4426950408889634f);
        }
        __syncthreads();

        #pragma unroll
        for (int nt = 0; nt < 3; ++nt) {
            f32x16 acc = {};
            #pragma unroll
            for (int kk = 0; kk < 6; ++kk) {
                f16x8 a = *(const f16x8*)&sq[(w * 32 + l31) * PAP + kk * 16 + h * 8];
                f16x8 b = *(const f16x8*)&sWT[(nt * 32 + l31) * PAP + kk * 16 + h * 8];
                acc = mfma_f16(a, b, acc);
            }
            int c = nt * 32 + l31;
            if (c < QPITCH) {
                #pragma unroll
                for (int r = 0; r < 16; ++r) {
                    int row = (r & 3) + 8 * (r >> 2) + 4 * h;
                    Qh[(q0 + w * 32 + row) * QPITCH + c] = (_Float16)acc[r];
                }
            }
        }
        return;
    }

    // ---- pair side: x -> Af + Xf ----
    _Float16* Af = (_Float16*)Af_u;
    __bf16*   Xf = (__bf16*)Xf_u;
    __shared__ _Float16 sxh[128 * PAP];   // cols: 0..65 = x, 66 = 1.0, 67.. = 0
    const long n0 = (long)blockIdx.x * 128;

    for (int i = tid; i < 128 * PAP / 2; i += 256) ((unsigned*)sxh)[i] = 0u;
    __syncthreads();
    for (int i = tid; i < 128 * 33; i += 256) {
        int r = i / 33, c2 = (i % 33) * 2;
        f32x2 v = *(const f32x2*)&x[(n0 + r) * DIM + c2];
        sxh[r * PAP + c2]     = (_Float16)v.x;
        sxh[r * PAP + c2 + 1] = (_Float16)v.y;
    }
    for (int r = tid; r < 128; r += 256) sxh[r * PAP + DIM] = (_Float16)1.0f;
    __syncthreads();

    // Af emission: [tile][kk][lane][8] (col 66 = 1 harmless: Qh cols 66+ are 0)
    for (int i = 0; i < 5; ++i) {
        int slot = i * 256 + tid;
        int tt = slot / 320, rem = slot % 320;
        int kk = rem / 64, l = rem % 64;
        const _Float16* src = &sxh[(32 * tt + (l & 31)) * PAP + kk * 16 + (l >> 5) * 8];
        f16x4 lo = *(const f16x4*)src;
        f16x4 hi = *(const f16x4*)(src + 4);
        f16x8 v = __builtin_shufflevector(lo, hi, 0, 1, 2, 3, 4, 5, 6, 7);
        *(f16x8*)&Af[((long)blockIdx.x * 4 + tt) * KFT + kk * 512 + l * 8] = v;
    }
    // Xf emission (branch-free): [tile][c=par*3+dt][lane][8] = X^T[d][pair]
    for (int i = 0; i < 6; ++i) {
        int slot = i * 256 + tid;
        int tt = slot / 384, rem = slot % 384;
        int c = rem / 64, l = rem % 64;
        int dt = c % 3, par = c / 3;
        int d = 32 * dt + (l & 31);
        int p0 = 32 * tt + 16 * par + 8 * (l >> 5);
        bf16x8 v;
        #pragma unroll
        for (int j = 0; j < 8; ++j)
            v[j] = (__bf16)(float)sxh[(p0 + j) * PAP + d];
        *(bf16x8*)&Xf[((long)blockIdx.x * 4 + tt) * XFT + c * 512 + l * 8] = v;
    }
}

// ---------------------------------------------------------------------------
// Flash (R23): grid = 64 qblocks * NS = 1024; 256 thr = 4 waves, each wave
// owns 32 q (qt=1). 1-tile LDS chunks {K(t+1), X(t)} double-buffered
// (22.5 KB/block), staged once per block via global_load_lds, consumed via
// ds_read_b128. One barrier per tile; staging issued a full tile ahead.
// Partials BF16, layout [q][NS][68]; col 66 = denominator.
// ---------------------------------------------------------------------------
__global__ __launch_bounds__(256, 4) void flash_kernel(
    const unsigned short* __restrict__ Qh_u, const unsigned short* __restrict__ Af_u,
    const unsigned short* __restrict__ Xf_u, unsigned short* __restrict__ Part_u) {
    const _Float16* Qh = (const _Float16*)Qh_u;
    const _Float16* Af = (const _Float16*)Af_u;
    const __bf16*   Xf = (const __bf16*)Xf_u;
    __bf16* Part = (__bf16*)Part_u;

    const int tid = threadIdx.x;
    const int lane = tid & 63, wave = tid >> 6;
    const int l31 = lane & 31, h = lane >> 5;
    const int qb = blockIdx.x / NS, ns = blockIdx.x % NS;
    const int tiles = NTILES / NS;            // 128
    const int qbase = qb * 128 + wave * 32;

    const char* Kg = (const char*)(Af + (long)(ns * tiles) * KFT);
    const char* Xg = (const char*)(Xf + (long)(ns * tiles) * XFT);

    __shared__ __align__(16) char smem[2 * CH_B];   // 22528 B

    // stage chunk for tile t into parity pb: K(t+1) then X(t)
    auto stage = [&](int t, int pb) {
        char* bK = smem + pb * CH_B;
        char* bX = bK + TILE_K_B;
        long ka = (t + 1 < tiles) ? (long)(t + 1) : (long)(tiles - 1);
        long xa = (long)t;
        gload16(Kg + ka * TILE_K_B + tid * 16, bK + tid * 16);          // 4 KB
        if (tid < 64)
            gload16(Kg + ka * TILE_K_B + 4096 + tid * 16, bK + 4096 + tid * 16); // 1 KB
        gload16(Xg + xa * TILE_X_B + tid * 16, bX + tid * 16);          // 4 KB
        if (tid < 128)
            gload16(Xg + xa * TILE_X_B + 4096 + tid * 16, bX + 4096 + tid * 16); // 2 KB
    };

    f16x8 aQ[5];
    #pragma unroll
    for (int kk = 0; kk < 5; ++kk)
        aQ[kk] = *(const f16x8*)&Qh[(long)(qbase + l31) * QPITCH + kk * 16 + h * 8];

    f32x16 o[3] = {};
    f32x16 s0;

    // prologue: stage chunk 0 {K(1),X(0)}; initial scores from K(0) (global)
    stage(0, 0);
    {
        const _Float16* kf = Af + (long)(ns * tiles) * KFT + lane * 8;
        f16x8 kA[5];
        #pragma unroll
        for (int kk = 0; kk < 5; ++kk) kA[kk] = *(const f16x8*)(kf + kk * 512);
        f32x16 a = {};
        #pragma unroll
        for (int kk = 0; kk < 5; ++kk) a = mfma_f16(kA[kk], aQ[kk], a);
        s0 = a;
    }
    __syncthreads();   // chunk 0 visible

    for (int t = 0; t < tiles; ++t) {
        if (t + 1 < tiles) stage(t + 1, (t + 1) & 1);
        const char* bK = smem + (t & 1) * CH_B;
        const char* bX = bK + TILE_K_B;

        f16x8 kR[5];   // K(t+1)
        #pragma unroll
        for (int kk = 0; kk < 5; ++kk)
            kR[kk] = *(const f16x8*)(bK + kk * 1024 + lane * 16);
        bf16x8 xR[6];  // X(t)
        #pragma unroll
        for (int cc = 0; cc < 6; ++cc)
            xR[cc] = *(const bf16x8*)(bX + cc * 1024 + lane * 16);

        U4 f0[2];
        makefrags(s0, f0);
        {
            f32x16 nsv = {};
            #pragma unroll
            for (int kk = 0; kk < 5; ++kk) nsv = mfma_f16(kR[kk], aQ[kk], nsv);
            s0 = nsv;
        }
        #pragma unroll
        for (int par = 0; par < 2; ++par)
            #pragma unroll
            for (int dt = 0; dt < 3; ++dt)
                o[dt] = mfma_bf16(f0[par].v, xR[par * 3 + dt], o[dt]);

        __syncthreads();   // chunk t reads done; chunk t+1 staging landed
    }

    // epilogue: bf16 partials [q][NS][68]; col 66 = denominator
    #pragma unroll
    for (int dt = 0; dt < 3; ++dt)
        #pragma unroll
        for (int r = 0; r < 16; ++r) {
            int row = (r & 3) + 8 * (r >> 2) + 4 * h;
            int q = qbase + row;
            int d = dt * 32 + l31;
            if (d < DIM + 1)
                Part[((long)q * NS + ns) * PARTP + d] = (__bf16)o[dt][r];
        }
}

// ---------------------------------------------------------------------------
// Combine: out[q][d] = sum_s Part[q][s][d] / sum_s Part[q][s][66]
// Part rows for one q are contiguous (NS*136 B).
// ---------------------------------------------------------------------------
__global__ __launch_bounds__(256) void combine_kernel(
    const unsigned short* __restrict__ Part_u, float* __restrict__ out) {
    const __bf16* Part = (const __bf16*)Part_u;
    int q = blockIdx.x * 2 + (threadIdx.x >> 7);
    int d = threadIdx.x & 127;
    if (d >= DIM) return;
    const __bf16* base = Part + (long)q * NS * PARTP;
    float num = 0.f, den = 0.f;
    #pragma unroll 4
    for (int s = 0; s < NS; ++s) {
        num += (float)base[s * PARTP + d];
        den += (float)base[s * PARTP + DIM];
    }
    out[(long)q * DIM + d] = num / den;
}

// ---------------------------------------------------------------------------
// Workspace: Qh @0 (1,310,720 B) ; Af @1,310,720 (10,485,760 B) ;
//            Xf @11,796,480 (12,582,912 B) ; Part @24,379,392 (17,825,792 B)
// ---------------------------------------------------------------------------
extern "C" void kernel_launch(void* const* d_in, const int* in_sizes, int n_in,
                              void* d_out, int out_size, void* d_ws, size_t ws_size,
                              hipStream_t stream) {
    const float* x     = (const float*)d_in[0];
    const float* query = (const float*)d_in[1];
    const float* Wk    = (const float*)d_in[2];
    float* out = (float*)d_out;
    char* ws = (char*)d_ws;

    unsigned short* Qh   = (unsigned short*)(ws + 0);
    unsigned short* Af   = (unsigned short*)(ws + 1310720);
    unsigned short* Xf   = (unsigned short*)(ws + 11796480);
    unsigned short* Part = (unsigned short*)(ws + 24379392);

    prep_kernel<<<512 + NUM_Q / 128, 256, 0, stream>>>(x, query, Wk, Af, Xf, Qh);
    flash_kernel<<<(NUM_Q / 128) * NS, 256, 0, stream>>>(Qh, Af, Xf, Part);
    combine_kernel<<<NUM_Q / 2, 256, 0, stream>>>(Part, out);
}

// Round 11
// 249.748 us; speedup vs baseline: 1.1284x; 1.1284x over previous
//
#include <hip/hip_runtime.h>
#include <cstdint>

// ---------------------------------------------------------------------------
// AttentionSelector: selected = softmax(query @ (x@Wk^T+bk)^T) @ x
// R13: 3-dispatch spine, Part BF16. VERIFIED 259.3 (flash 181.5).
// R15-R19: schedule/hint edits null or negative; permlane hazard found+fixed
//      (s_nop-hardened plswap, R18-verified).
// R20: LDS chunk staging WIN — total 249.6, flash 171.5. BEST VERIFIED.
// R21 desync NULL (254.1). R22 K-global/X-LDS split REGRESSED (189.3 flash).
// R23 qt=1 (occupancy 2x) REGRESSED (202.2 flash): halving the q-tile halves
//      q-rows served per LDS read -> per-CU LDS+L2 traffic DOUBLED; time
//      followed traffic, not occupancy.
// CONCLUSION: qt=2 + block-shared LDS staging is traffic-optimal for this
//      shape; R20 is the verified optimum (MFMA ~44%, LDS ~41%, dependency
//      chain ~remainder — no single saturated resource; 6 structural
//      experiments failed to beat it).
// R24: byte-exact revert to R20.
// ---------------------------------------------------------------------------

typedef __bf16    bf16x4 __attribute__((ext_vector_type(4)));
typedef __bf16    bf16x8 __attribute__((ext_vector_type(8)));
typedef _Float16  f16x4  __attribute__((ext_vector_type(4)));
typedef _Float16  f16x8  __attribute__((ext_vector_type(8)));
typedef float     f32x2  __attribute__((ext_vector_type(2)));
typedef float     f32x16 __attribute__((ext_vector_type(16)));

extern "C" __device__ float __ocml_native_exp2_f32(float);

#define NUM_PAIRS   65536
#define NUM_Q       8192
#define DIM         66
#define QPITCH      80        // Qh row pitch (f16)
#define KFT         2560      // Af f16 per 32-pair tile (5 kk x 512)
#define XFT         3072      // Xf bf16 per 32-pair tile (6 c x 512)
#define PARTP       68        // partial row pitch (bf16)
#define NS          16
#define NTILES      (NUM_PAIRS/32)   // 2048

#define KBYTES      5120      // Af bytes per tile
#define XBYTES      6144      // Xf bytes per tile
#define CHUNK_K     (2*KBYTES)          // 10240
#define CHUNK_X     (2*XBYTES)          // 12288
#define CHUNK_BYTES (CHUNK_K+CHUNK_X)   // 22528

__device__ __forceinline__ f32x16 mfma_bf16(bf16x8 a, bf16x8 b, f32x16 c) {
    return __builtin_amdgcn_mfma_f32_32x32x16_bf16(a, b, c, 0, 0, 0);
}
__device__ __forceinline__ f32x16 mfma_f16(f16x8 a, f16x8 b, f32x16 c) {
    return __builtin_amdgcn_mfma_f32_32x32x16_f16(a, b, c, 0, 0, 0);
}
// gfx950: exchange lanes 32..63 of a with lanes 0..31 of b.
// HAZARD-HARDENED (R18, verified): VALU-write -> permlane-read needs wait
// states; compiler can't see inside inline asm, so carry our own s_nop.
__device__ __forceinline__ void plswap(unsigned &a, unsigned &b) {
    asm volatile("s_nop 1\n\t"
                 "v_permlane32_swap_b32 %0, %1\n\t"
                 "s_nop 1"
                 : "+v"(a), "+v"(b));
}
__device__ __forceinline__ unsigned packbf(float a, float b) {
    union { __bf16 h[2]; unsigned u; } t;
    t.h[0] = (__bf16)a; t.h[1] = (__bf16)b;
    return t.u;
}
union U4 { unsigned u[4]; bf16x8 v; };

// async global->LDS, 16B per lane, linear dest (wave base + lane*16)
__device__ __forceinline__ void gload16(const void* g, void* l) {
    __builtin_amdgcn_global_load_lds(
        (const __attribute__((address_space(1))) unsigned int*)g,
        (__attribute__((address_space(3))) unsigned int*)l,
        16, 0, 0);
}

// Sᵀ C-tile (col=query l31, row(pair)=(r&3)+8*(r>>2)+4h) -> exp2 -> two PV
// A-frags (par0: pairs 0..15, par1: 16..31) via permlane32_swap (verified).
__device__ __forceinline__ void makefrags(const f32x16 &s, U4 *f) {
    float P[16];
    #pragma unroll
    for (int r = 0; r < 16; ++r) P[r] = __ocml_native_exp2_f32(s[r]);
    unsigned E0 = packbf(P[0],  P[1]),  E1 = packbf(P[2],  P[3]);
    unsigned F0 = packbf(P[4],  P[5]),  F1 = packbf(P[6],  P[7]);
    plswap(E0, F0); plswap(E1, F1);
    f[0].u[0] = E0; f[0].u[1] = E1; f[0].u[2] = F0; f[0].u[3] = F1;
    unsigned G0 = packbf(P[8],  P[9]),  G1 = packbf(P[10], P[11]);
    unsigned H0 = packbf(P[12], P[13]), H1 = packbf(P[14], P[15]);
    plswap(G0, H0); plswap(G1, H1);
    f[1].u[0] = G0; f[1].u[1] = G1; f[1].u[2] = H0; f[1].u[3] = H1;
}

// ---------------------------------------------------------------------------
// Prep: blocks 0..511 -> 128 pairs each: x -> Af (f16 S-frags) + Xf (bf16 PV
//       frags, ones-trick for row 66). blocks 512..575 -> 128 queries each:
//       Qh = (Wk^T q)*log2e via mfma f16.   (unchanged, verified)
// ---------------------------------------------------------------------------
#define PAP 104   // LDS pitch (f16)
__global__ __launch_bounds__(256) void prep_kernel(
    const float* __restrict__ x, const float* __restrict__ query,
    const float* __restrict__ Wk,
    unsigned short* __restrict__ Af_u, unsigned short* __restrict__ Xf_u,
    unsigned short* __restrict__ Qh_u) {
    const int tid = threadIdx.x;
    const int lane = tid & 63, w = tid >> 6;
    const int l31 = lane & 31, h = lane >> 5;

    if (blockIdx.x >= 512) {
        // ---- query side: Qh = (Wk^T q) * log2e via mfma ----
        __shared__ _Float16 sq[128 * PAP];    // query rows f16, pads 0
        __shared__ _Float16 sWT[96 * PAP];    // sWT[e][d] = Wk[d][e]*log2e, pads 0
        _Float16* Qh = (_Float16*)Qh_u;
        const long q0 = (long)(blockIdx.x - 512) * 128;

        for (int i = tid; i < 128 * PAP / 2; i += 256) ((unsigned*)sq)[i] = 0u;
        for (int i = tid; i < 96 * PAP / 2; i += 256)  ((unsigned*)sWT)[i] = 0u;
        __syncthreads();

        for (int i = tid; i < 128 * 33; i += 256) {       // f32x2 loads
            int r = i / 33, c2 = (i % 33) * 2;
            f32x2 v = *(const f32x2*)&query[(q0 + r) * DIM + c2];
            sq[r * PAP + c2]     = (_Float16)v.x;
            sq[r * PAP + c2 + 1] = (_Float16)v.y;
        }
        for (int i = tid; i < DIM * 33; i += 256) {       // Wk transposed, scaled
            int d = i / 33, e2 = (i % 33) * 2;
            f32x2 v = *(const f32x2*)&Wk[d * DIM + e2];
            sWT[e2 * PAP + d]       = (_Float16)(v.x * 1.4426950408889634f);
            sWT[(e2 + 1) * PAP + d] = (_Float16)(v.y * 1.4426950408889634f);
        }
        __syncthreads();

        #pragma unroll
        for (int nt = 0; nt < 3; ++nt) {
            f32x16 acc = {};
            #pragma unroll
            for (int kk = 0; kk < 6; ++kk) {
                f16x8 a = *(const f16x8*)&sq[(w * 32 + l31) * PAP + kk * 16 + h * 8];
                f16x8 b = *(const f16x8*)&sWT[(nt * 32 + l31) * PAP + kk * 16 + h * 8];
                acc = mfma_f16(a, b, acc);
            }
            int c = nt * 32 + l31;
            if (c < QPITCH) {
                #pragma unroll
                for (int r = 0; r < 16; ++r) {
                    int row = (r & 3) + 8 * (r >> 2) + 4 * h;
                    Qh[(q0 + w * 32 + row) * QPITCH + c] = (_Float16)acc[r];
                }
            }
        }
        return;
    }

    // ---- pair side: x -> Af + Xf ----
    _Float16* Af = (_Float16*)Af_u;
    __bf16*   Xf = (__bf16*)Xf_u;
    __shared__ _Float16 sxh[128 * PAP];   // cols: 0..65 = x, 66 = 1.0, 67.. = 0
    const long n0 = (long)blockIdx.x * 128;

    for (int i = tid; i < 128 * PAP / 2; i += 256) ((unsigned*)sxh)[i] = 0u;
    __syncthreads();
    for (int i = tid; i < 128 * 33; i += 256) {
        int r = i / 33, c2 = (i % 33) * 2;
        f32x2 v = *(const f32x2*)&x[(n0 + r) * DIM + c2];
        sxh[r * PAP + c2]     = (_Float16)v.x;
        sxh[r * PAP + c2 + 1] = (_Float16)v.y;
    }
    for (int r = tid; r < 128; r += 256) sxh[r * PAP + DIM] = (_Float16)1.0f;
    __syncthreads();

    // Af emission: [tile][kk][lane][8] (col 66 = 1 harmless: Qh cols 66+ are 0)
    for (int i = 0; i < 5; ++i) {
        int slot = i * 256 + tid;
        int tt = slot / 320, rem = slot % 320;
        int kk = rem / 64, l = rem % 64;
        const _Float16* src = &sxh[(32 * tt + (l & 31)) * PAP + kk * 16 + (l >> 5) * 8];
        f16x4 lo = *(const f16x4*)src;
        f16x4 hi = *(const f16x4*)(src + 4);
        f16x8 v = __builtin_shufflevector(lo, hi, 0, 1, 2, 3, 4, 5, 6, 7);
        *(f16x8*)&Af[((long)blockIdx.x * 4 + tt) * KFT + kk * 512 + l * 8] = v;
    }
    // Xf emission (branch-free): [tile][c=par*3+dt][lane][8] = X^T[d][pair]
    for (int i = 0; i < 6; ++i) {
        int slot = i * 256 + tid;
        int tt = slot / 384, rem = slot % 384;
        int c = rem / 64, l = rem % 64;
        int dt = c % 3, par = c / 3;
        int d = 32 * dt + (l & 31);
        int p0 = 32 * tt + 16 * par + 8 * (l >> 5);
        bf16x8 v;
        #pragma unroll
        for (int j = 0; j < 8; ++j)
            v[j] = (__bf16)(float)sxh[(p0 + j) * PAP + d];
        *(bf16x8*)&Xf[((long)blockIdx.x * 4 + tt) * XFT + c * 512 + l * 8] = v;
    }
}

// ---------------------------------------------------------------------------
// Flash (R20, verified): grid = 32 qblocks * NS; 256 thr = 4 waves x 64 q
// (qt=2). 2-tile chunks staged once per block into double-buffered LDS (44KB)
// via global_load_lds; all 4 waves consume via ds_read_b128 (2-way bank =
// free). K-chunk(c) = {K(2c+1),K(2c+2)}; X-chunk(c) = {X(2c),X(2c+1)}.
// One barrier per chunk; staging issued a full chunk ahead.
// Partials BF16, layout [q][NS][68]; col 66 = denominator.
// ---------------------------------------------------------------------------
__global__ __launch_bounds__(256, 2) void flash_kernel(
    const unsigned short* __restrict__ Qh_u, const unsigned short* __restrict__ Af_u,
    const unsigned short* __restrict__ Xf_u, unsigned short* __restrict__ Part_u) {
    const _Float16* Qh = (const _Float16*)Qh_u;
    const _Float16* Af = (const _Float16*)Af_u;
    const __bf16*   Xf = (const __bf16*)Xf_u;
    __bf16* Part = (__bf16*)Part_u;

    const int tid = threadIdx.x;
    const int lane = tid & 63, wave = tid >> 6;
    const int l31 = lane & 31, h = lane >> 5;
    const int qb = blockIdx.x / NS, ns = blockIdx.x % NS;
    const int tiles = NTILES / NS;            // 128
    const int qbase = qb * 256 + wave * 64;

    const char* Kg = (const char*)(Af + (long)(ns * tiles) * KFT);
    const char* Xg = (const char*)(Xf + (long)(ns * tiles) * XFT);

    __shared__ __align__(16) char smem[2 * CHUNK_BYTES];   // 45056 B

    // stage chunk m into buffer parity pb: K{2m+1,2m+2}, X{2m,2m+1}
    auto stage = [&](int m, int pb) {
        char* bK = smem + pb * CHUNK_BYTES;
        char* bX = bK + CHUNK_K;
        long ka = (2 * m + 1 < tiles) ? 2 * m + 1 : tiles - 1;
        long kb = (2 * m + 2 < tiles) ? 2 * m + 2 : tiles - 1;
        long xa = (2 * m     < tiles) ? 2 * m     : tiles - 1;
        long xb = (2 * m + 1 < tiles) ? 2 * m + 1 : tiles - 1;
        gload16(Kg + ka * KBYTES + tid * 16, bK + tid * 16);
        gload16(Kg + kb * KBYTES + tid * 16, bK + KBYTES + tid * 16);
        gload16(Xg + xa * XBYTES + tid * 16, bX + tid * 16);
        gload16(Xg + xb * XBYTES + tid * 16, bX + XBYTES + tid * 16);
        if (tid < 64) {          // wave 0: K tail 1KB each
            gload16(Kg + ka * KBYTES + 4096 + tid * 16, bK + 4096 + tid * 16);
            gload16(Kg + kb * KBYTES + 4096 + tid * 16, bK + KBYTES + 4096 + tid * 16);
        }
        if (tid < 128) {         // waves 0,1: X tail 2KB each
            gload16(Xg + xa * XBYTES + 4096 + tid * 16, bX + 4096 + tid * 16);
            gload16(Xg + xb * XBYTES + 4096 + tid * 16, bX + XBYTES + 4096 + tid * 16);
        }
    };

    f16x8 aQ[2][5];
    #pragma unroll
    for (int qt = 0; qt < 2; ++qt)
        #pragma unroll
        for (int kk = 0; kk < 5; ++kk)
            aQ[qt][kk] = *(const f16x8*)&Qh[(long)(qbase + qt * 32 + l31) * QPITCH + kk * 16 + h * 8];

    f32x16 o[2][3] = {};
    f32x16 s0, s1;

    // prologue: stage chunk 0; direct-load K(0) for the initial scores
    stage(0, 0);
    {
        f16x8 kA[5];
        #pragma unroll
        for (int kk = 0; kk < 5; ++kk)
            kA[kk] = *(const f16x8*)(Kg + kk * 1024 + lane * 16);
        f32x16 a = {}, b = {};
        #pragma unroll
        for (int kk = 0; kk < 5; ++kk) {
            a = mfma_f16(kA[kk], aQ[0][kk], a);
            b = mfma_f16(kA[kk], aQ[1][kk], b);
        }
        s0 = a; s1 = b;
    }
    __syncthreads();   // staging of chunk 0 visible

    for (int c = 0; c < tiles / 2; ++c) {
        if (c + 1 < tiles / 2) stage(c + 1, (c + 1) & 1);
        const char* bK = smem + (c & 1) * CHUNK_BYTES;
        const char* bX = bK + CHUNK_K;
        #pragma unroll
        for (int p = 0; p < 2; ++p) {
            f16x8 kR[5];
            #pragma unroll
            for (int kk = 0; kk < 5; ++kk)
                kR[kk] = *(const f16x8*)(bK + p * KBYTES + kk * 1024 + lane * 16);
            bf16x8 xR[6];
            #pragma unroll
            for (int cc = 0; cc < 6; ++cc)
                xR[cc] = *(const bf16x8*)(bX + p * XBYTES + cc * 1024 + lane * 16);

            U4 f0[2];
            makefrags(s0, f0);
            {
                f32x16 nsv = {};
                #pragma unroll
                for (int kk = 0; kk < 5; ++kk) nsv = mfma_f16(kR[kk], aQ[0][kk], nsv);
                s0 = nsv;
            }
            #pragma unroll
            for (int par = 0; par < 2; ++par)
                #pragma unroll
                for (int dt = 0; dt < 3; ++dt)
                    o[0][dt] = mfma_bf16(f0[par].v, xR[par * 3 + dt], o[0][dt]);

            U4 f1[2];
            makefrags(s1, f1);
            {
                f32x16 nsv = {};
                #pragma unroll
                for (int kk = 0; kk < 5; ++kk) nsv = mfma_f16(kR[kk], aQ[1][kk], nsv);
                s1 = nsv;
            }
            #pragma unroll
            for (int par = 0; par < 2; ++par)
                #pragma unroll
                for (int dt = 0; dt < 3; ++dt)
                    o[1][dt] = mfma_bf16(f1[par].v, xR[par * 3 + dt], o[1][dt]);
        }
        __syncthreads();   // chunk c reads done; chunk c+1 staging landed
    }

    // epilogue: bf16 partials [q][NS][68]; col 66 = denominator
    #pragma unroll
    for (int qt = 0; qt < 2; ++qt)
        #pragma unroll
        for (int dt = 0; dt < 3; ++dt)
            #pragma unroll
            for (int r = 0; r < 16; ++r) {
                int row = (r & 3) + 8 * (r >> 2) + 4 * h;
                int q = qbase + qt * 32 + row;
                int d = dt * 32 + l31;
                if (d < DIM + 1)
                    Part[((long)q * NS + ns) * PARTP + d] = (__bf16)o[qt][dt][r];
            }
}

// ---------------------------------------------------------------------------
// Combine: out[q][d] = sum_s Part[q][s][d] / sum_s Part[q][s][66]
// Part rows for one q are contiguous (NS*136 B).
// ---------------------------------------------------------------------------
__global__ __launch_bounds__(256) void combine_kernel(
    const unsigned short* __restrict__ Part_u, float* __restrict__ out) {
    const __bf16* Part = (const __bf16*)Part_u;
    int q = blockIdx.x * 2 + (threadIdx.x >> 7);
    int d = threadIdx.x & 127;
    if (d >= DIM) return;
    const __bf16* base = Part + (long)q * NS * PARTP;
    float num = 0.f, den = 0.f;
    #pragma unroll 4
    for (int s = 0; s < NS; ++s) {
        num += (float)base[s * PARTP + d];
        den += (float)base[s * PARTP + DIM];
    }
    out[(long)q * DIM + d] = num / den;
}

// ---------------------------------------------------------------------------
// Workspace: Qh @0 (1,310,720 B) ; Af @1,310,720 (10,485,760 B) ;
//            Xf @11,796,480 (12,582,912 B) ; Part @24,379,392 (17,825,792 B)
// ---------------------------------------------------------------------------
extern "C" void kernel_launch(void* const* d_in, const int* in_sizes, int n_in,
                              void* d_out, int out_size, void* d_ws, size_t ws_size,
                              hipStream_t stream) {
    const float* x     = (const float*)d_in[0];
    const float* query = (const float*)d_in[1];
    const float* Wk    = (const float*)d_in[2];
    float* out = (float*)d_out;
    char* ws = (char*)d_ws;

    unsigned short* Qh   = (unsigned short*)(ws + 0);
    unsigned short* Af   = (unsigned short*)(ws + 1310720);
    unsigned short* Xf   = (unsigned short*)(ws + 11796480);
    unsigned short* Part = (unsigned short*)(ws + 24379392);

    prep_kernel<<<512 + NUM_Q / 128, 256, 0, stream>>>(x, query, Wk, Af, Xf, Qh);
    flash_kernel<<<(NUM_Q / 256) * NS, 256, 0, stream>>>(Qh, Af, Xf, Part);
    combine_kernel<<<NUM_Q / 2, 256, 0, stream>>>(Part, out);
}

// Round 12
// 248.019 us; speedup vs baseline: 1.1363x; 1.0070x over previous
//
#include <hip/hip_runtime.h>
#include <cstdint>

// ---------------------------------------------------------------------------
// AttentionSelector: selected = softmax(query @ (x@Wk^T+bk)^T) @ x
// R13: 3-dispatch spine, Part BF16. VERIFIED 259.3 (flash 181.5).
// R15-R19: schedule/hint edits null or negative; permlane hazard found+fixed
//      (s_nop-hardened plswap, R18-verified).
// R20: LDS chunk staging WIN — total 249.6, flash 171.5. BEST VERIFIED.
// R21 desync NULL. R22 K-global/X-LDS split REGRESSED. R23 qt=1 REGRESSED
//      (occupancy 2x but per-CU traffic 2x; time follows traffic).
// R24: revert to R20 reproduced: 249.7 (flash 173.6). Flash is exhausted in
//      this structure: critical-path bound at register-walled 2 waves/SIMD;
//      all levers (occupancy/traffic/schedule/desync/split) measured dead.
// R25: attack the unprofiled 76us tail at the only low-risk point: combine
//      v2. One wave per 2 q; lane j reads u32 bf16-pairs (d=2j,2j+1)
//      coalesced; lanes 0-1 take the d64..67 tail (pair 33 low half = the
//      denominator, high half = pad, accumulated but unused); den broadcast
//      via shfl. Same summation order + division => same numerics.
//      Grid 4096 -> 1024 blocks; 32 scalar loads/thread -> ~17 u32 loads.
//      flash & prep byte-identical to R24.
// ---------------------------------------------------------------------------

typedef __bf16    bf16x4 __attribute__((ext_vector_type(4)));
typedef __bf16    bf16x8 __attribute__((ext_vector_type(8)));
typedef _Float16  f16x4  __attribute__((ext_vector_type(4)));
typedef _Float16  f16x8  __attribute__((ext_vector_type(8)));
typedef float     f32x2  __attribute__((ext_vector_type(2)));
typedef float     f32x16 __attribute__((ext_vector_type(16)));

extern "C" __device__ float __ocml_native_exp2_f32(float);

#define NUM_PAIRS   65536
#define NUM_Q       8192
#define DIM         66
#define QPITCH      80        // Qh row pitch (f16)
#define KFT         2560      // Af f16 per 32-pair tile (5 kk x 512)
#define XFT         3072      // Xf bf16 per 32-pair tile (6 c x 512)
#define PARTP       68        // partial row pitch (bf16)
#define NS          16
#define NTILES      (NUM_PAIRS/32)   // 2048

#define KBYTES      5120      // Af bytes per tile
#define XBYTES      6144      // Xf bytes per tile
#define CHUNK_K     (2*KBYTES)          // 10240
#define CHUNK_X     (2*XBYTES)          // 12288
#define CHUNK_BYTES (CHUNK_K+CHUNK_X)   // 22528

__device__ __forceinline__ f32x16 mfma_bf16(bf16x8 a, bf16x8 b, f32x16 c) {
    return __builtin_amdgcn_mfma_f32_32x32x16_bf16(a, b, c, 0, 0, 0);
}
__device__ __forceinline__ f32x16 mfma_f16(f16x8 a, f16x8 b, f32x16 c) {
    return __builtin_amdgcn_mfma_f32_32x32x16_f16(a, b, c, 0, 0, 0);
}
// gfx950: exchange lanes 32..63 of a with lanes 0..31 of b.
// HAZARD-HARDENED (R18, verified): VALU-write -> permlane-read needs wait
// states; compiler can't see inside inline asm, so carry our own s_nop.
__device__ __forceinline__ void plswap(unsigned &a, unsigned &b) {
    asm volatile("s_nop 1\n\t"
                 "v_permlane32_swap_b32 %0, %1\n\t"
                 "s_nop 1"
                 : "+v"(a), "+v"(b));
}
__device__ __forceinline__ unsigned packbf(float a, float b) {
    union { __bf16 h[2]; unsigned u; } t;
    t.h[0] = (__bf16)a; t.h[1] = (__bf16)b;
    return t.u;
}
union U4 { unsigned u[4]; bf16x8 v; };

// async global->LDS, 16B per lane, linear dest (wave base + lane*16)
__device__ __forceinline__ void gload16(const void* g, void* l) {
    __builtin_amdgcn_global_load_lds(
        (const __attribute__((address_space(1))) unsigned int*)g,
        (__attribute__((address_space(3))) unsigned int*)l,
        16, 0, 0);
}

// bf16 pair (packed in u32) -> two exact f32
__device__ __forceinline__ float bf16lo(unsigned u) {
    union { unsigned u; float f; } t; t.u = u << 16; return t.f;
}
__device__ __forceinline__ float bf16hi(unsigned u) {
    union { unsigned u; float f; } t; t.u = u & 0xffff0000u; return t.f;
}

// Sᵀ C-tile (col=query l31, row(pair)=(r&3)+8*(r>>2)+4h) -> exp2 -> two PV
// A-frags (par0: pairs 0..15, par1: 16..31) via permlane32_swap (verified).
__device__ __forceinline__ void makefrags(const f32x16 &s, U4 *f) {
    float P[16];
    #pragma unroll
    for (int r = 0; r < 16; ++r) P[r] = __ocml_native_exp2_f32(s[r]);
    unsigned E0 = packbf(P[0],  P[1]),  E1 = packbf(P[2],  P[3]);
    unsigned F0 = packbf(P[4],  P[5]),  F1 = packbf(P[6],  P[7]);
    plswap(E0, F0); plswap(E1, F1);
    f[0].u[0] = E0; f[0].u[1] = E1; f[0].u[2] = F0; f[0].u[3] = F1;
    unsigned G0 = packbf(P[8],  P[9]),  G1 = packbf(P[10], P[11]);
    unsigned H0 = packbf(P[12], P[13]), H1 = packbf(P[14], P[15]);
    plswap(G0, H0); plswap(G1, H1);
    f[1].u[0] = G0; f[1].u[1] = G1; f[1].u[2] = H0; f[1].u[3] = H1;
}

// ---------------------------------------------------------------------------
// Prep: blocks 0..511 -> 128 pairs each: x -> Af (f16 S-frags) + Xf (bf16 PV
//       frags, ones-trick for row 66). blocks 512..575 -> 128 queries each:
//       Qh = (Wk^T q)*log2e via mfma f16.   (unchanged, verified)
// ---------------------------------------------------------------------------
#define PAP 104   // LDS pitch (f16)
__global__ __launch_bounds__(256) void prep_kernel(
    const float* __restrict__ x, const float* __restrict__ query,
    const float* __restrict__ Wk,
    unsigned short* __restrict__ Af_u, unsigned short* __restrict__ Xf_u,
    unsigned short* __restrict__ Qh_u) {
    const int tid = threadIdx.x;
    const int lane = tid & 63, w = tid >> 6;
    const int l31 = lane & 31, h = lane >> 5;

    if (blockIdx.x >= 512) {
        // ---- query side: Qh = (Wk^T q) * log2e via mfma ----
        __shared__ _Float16 sq[128 * PAP];    // query rows f16, pads 0
        __shared__ _Float16 sWT[96 * PAP];    // sWT[e][d] = Wk[d][e]*log2e, pads 0
        _Float16* Qh = (_Float16*)Qh_u;
        const long q0 = (long)(blockIdx.x - 512) * 128;

        for (int i = tid; i < 128 * PAP / 2; i += 256) ((unsigned*)sq)[i] = 0u;
        for (int i = tid; i < 96 * PAP / 2; i += 256)  ((unsigned*)sWT)[i] = 0u;
        __syncthreads();

        for (int i = tid; i < 128 * 33; i += 256) {       // f32x2 loads
            int r = i / 33, c2 = (i % 33) * 2;
            f32x2 v = *(const f32x2*)&query[(q0 + r) * DIM + c2];
            sq[r * PAP + c2]     = (_Float16)v.x;
            sq[r * PAP + c2 + 1] = (_Float16)v.y;
        }
        for (int i = tid; i < DIM * 33; i += 256) {       // Wk transposed, scaled
            int d = i / 33, e2 = (i % 33) * 2;
            f32x2 v = *(const f32x2*)&Wk[d * DIM + e2];
            sWT[e2 * PAP + d]       = (_Float16)(v.x * 1.4426950408889634f);
            sWT[(e2 + 1) * PAP + d] = (_Float16)(v.y * 1.4426950408889634f);
        }
        __syncthreads();

        #pragma unroll
        for (int nt = 0; nt < 3; ++nt) {
            f32x16 acc = {};
            #pragma unroll
            for (int kk = 0; kk < 6; ++kk) {
                f16x8 a = *(const f16x8*)&sq[(w * 32 + l31) * PAP + kk * 16 + h * 8];
                f16x8 b = *(const f16x8*)&sWT[(nt * 32 + l31) * PAP + kk * 16 + h * 8];
                acc = mfma_f16(a, b, acc);
            }
            int c = nt * 32 + l31;
            if (c < QPITCH) {
                #pragma unroll
                for (int r = 0; r < 16; ++r) {
                    int row = (r & 3) + 8 * (r >> 2) + 4 * h;
                    Qh[(q0 + w * 32 + row) * QPITCH + c] = (_Float16)acc[r];
                }
            }
        }
        return;
    }

    // ---- pair side: x -> Af + Xf ----
    _Float16* Af = (_Float16*)Af_u;
    __bf16*   Xf = (__bf16*)Xf_u;
    __shared__ _Float16 sxh[128 * PAP];   // cols: 0..65 = x, 66 = 1.0, 67.. = 0
    const long n0 = (long)blockIdx.x * 128;

    for (int i = tid; i < 128 * PAP / 2; i += 256) ((unsigned*)sxh)[i] = 0u;
    __syncthreads();
    for (int i = tid; i < 128 * 33; i += 256) {
        int r = i / 33, c2 = (i % 33) * 2;
        f32x2 v = *(const f32x2*)&x[(n0 + r) * DIM + c2];
        sxh[r * PAP + c2]     = (_Float16)v.x;
        sxh[r * PAP + c2 + 1] = (_Float16)v.y;
    }
    for (int r = tid; r < 128; r += 256) sxh[r * PAP + DIM] = (_Float16)1.0f;
    __syncthreads();

    // Af emission: [tile][kk][lane][8] (col 66 = 1 harmless: Qh cols 66+ are 0)
    for (int i = 0; i < 5; ++i) {
        int slot = i * 256 + tid;
        int tt = slot / 320, rem = slot % 320;
        int kk = rem / 64, l = rem % 64;
        const _Float16* src = &sxh[(32 * tt + (l & 31)) * PAP + kk * 16 + (l >> 5) * 8];
        f16x4 lo = *(const f16x4*)src;
        f16x4 hi = *(const f16x4*)(src + 4);
        f16x8 v = __builtin_shufflevector(lo, hi, 0, 1, 2, 3, 4, 5, 6, 7);
        *(f16x8*)&Af[((long)blockIdx.x * 4 + tt) * KFT + kk * 512 + l * 8] = v;
    }
    // Xf emission (branch-free): [tile][c=par*3+dt][lane][8] = X^T[d][pair]
    for (int i = 0; i < 6; ++i) {
        int slot = i * 256 + tid;
        int tt = slot / 384, rem = slot % 384;
        int c = rem / 64, l = rem % 64;
        int dt = c % 3, par = c / 3;
        int d = 32 * dt + (l & 31);
        int p0 = 32 * tt + 16 * par + 8 * (l >> 5);
        bf16x8 v;
        #pragma unroll
        for (int j = 0; j < 8; ++j)
            v[j] = (__bf16)(float)sxh[(p0 + j) * PAP + d];
        *(bf16x8*)&Xf[((long)blockIdx.x * 4 + tt) * XFT + c * 512 + l * 8] = v;
    }
}

// ---------------------------------------------------------------------------
// Flash (R20, verified): grid = 32 qblocks * NS; 256 thr = 4 waves x 64 q
// (qt=2). 2-tile chunks staged once per block into double-buffered LDS (44KB)
// via global_load_lds; all 4 waves consume via ds_read_b128 (2-way bank =
// free). K-chunk(c) = {K(2c+1),K(2c+2)}; X-chunk(c) = {X(2c),X(2c+1)}.
// One barrier per chunk; staging issued a full chunk ahead.
// Partials BF16, layout [q][NS][68]; col 66 = denominator.
// ---------------------------------------------------------------------------
__global__ __launch_bounds__(256, 2) void flash_kernel(
    const unsigned short* __restrict__ Qh_u, const unsigned short* __restrict__ Af_u,
    const unsigned short* __restrict__ Xf_u, unsigned short* __restrict__ Part_u) {
    const _Float16* Qh = (const _Float16*)Qh_u;
    const _Float16* Af = (const _Float16*)Af_u;
    const __bf16*   Xf = (const __bf16*)Xf_u;
    __bf16* Part = (__bf16*)Part_u;

    const int tid = threadIdx.x;
    const int lane = tid & 63, wave = tid >> 6;
    const int l31 = lane & 31, h = lane >> 5;
    const int qb = blockIdx.x / NS, ns = blockIdx.x % NS;
    const int tiles = NTILES / NS;            // 128
    const int qbase = qb * 256 + wave * 64;

    const char* Kg = (const char*)(Af + (long)(ns * tiles) * KFT);
    const char* Xg = (const char*)(Xf + (long)(ns * tiles) * XFT);

    __shared__ __align__(16) char smem[2 * CHUNK_BYTES];   // 45056 B

    // stage chunk m into buffer parity pb: K{2m+1,2m+2}, X{2m,2m+1}
    auto stage = [&](int m, int pb) {
        char* bK = smem + pb * CHUNK_BYTES;
        char* bX = bK + CHUNK_K;
        long ka = (2 * m + 1 < tiles) ? 2 * m + 1 : tiles - 1;
        long kb = (2 * m + 2 < tiles) ? 2 * m + 2 : tiles - 1;
        long xa = (2 * m     < tiles) ? 2 * m     : tiles - 1;
        long xb = (2 * m + 1 < tiles) ? 2 * m + 1 : tiles - 1;
        gload16(Kg + ka * KBYTES + tid * 16, bK + tid * 16);
        gload16(Kg + kb * KBYTES + tid * 16, bK + KBYTES + tid * 16);
        gload16(Xg + xa * XBYTES + tid * 16, bX + tid * 16);
        gload16(Xg + xb * XBYTES + tid * 16, bX + XBYTES + tid * 16);
        if (tid < 64) {          // wave 0: K tail 1KB each
            gload16(Kg + ka * KBYTES + 4096 + tid * 16, bK + 4096 + tid * 16);
            gload16(Kg + kb * KBYTES + 4096 + tid * 16, bK + KBYTES + 4096 + tid * 16);
        }
        if (tid < 128) {         // waves 0,1: X tail 2KB each
            gload16(Xg + xa * XBYTES + 4096 + tid * 16, bX + 4096 + tid * 16);
            gload16(Xg + xb * XBYTES + 4096 + tid * 16, bX + XBYTES + 4096 + tid * 16);
        }
    };

    f16x8 aQ[2][5];
    #pragma unroll
    for (int qt = 0; qt < 2; ++qt)
        #pragma unroll
        for (int kk = 0; kk < 5; ++kk)
            aQ[qt][kk] = *(const f16x8*)&Qh[(long)(qbase + qt * 32 + l31) * QPITCH + kk * 16 + h * 8];

    f32x16 o[2][3] = {};
    f32x16 s0, s1;

    // prologue: stage chunk 0; direct-load K(0) for the initial scores
    stage(0, 0);
    {
        f16x8 kA[5];
        #pragma unroll
        for (int kk = 0; kk < 5; ++kk)
            kA[kk] = *(const f16x8*)(Kg + kk * 1024 + lane * 16);
        f32x16 a = {}, b = {};
        #pragma unroll
        for (int kk = 0; kk < 5; ++kk) {
            a = mfma_f16(kA[kk], aQ[0][kk], a);
            b = mfma_f16(kA[kk], aQ[1][kk], b);
        }
        s0 = a; s1 = b;
    }
    __syncthreads();   // staging of chunk 0 visible

    for (int c = 0; c < tiles / 2; ++c) {
        if (c + 1 < tiles / 2) stage(c + 1, (c + 1) & 1);
        const char* bK = smem + (c & 1) * CHUNK_BYTES;
        const char* bX = bK + CHUNK_K;
        #pragma unroll
        for (int p = 0; p < 2; ++p) {
            f16x8 kR[5];
            #pragma unroll
            for (int kk = 0; kk < 5; ++kk)
                kR[kk] = *(const f16x8*)(bK + p * KBYTES + kk * 1024 + lane * 16);
            bf16x8 xR[6];
            #pragma unroll
            for (int cc = 0; cc < 6; ++cc)
                xR[cc] = *(const bf16x8*)(bX + p * XBYTES + cc * 1024 + lane * 16);

            U4 f0[2];
            makefrags(s0, f0);
            {
                f32x16 nsv = {};
                #pragma unroll
                for (int kk = 0; kk < 5; ++kk) nsv = mfma_f16(kR[kk], aQ[0][kk], nsv);
                s0 = nsv;
            }
            #pragma unroll
            for (int par = 0; par < 2; ++par)
                #pragma unroll
                for (int dt = 0; dt < 3; ++dt)
                    o[0][dt] = mfma_bf16(f0[par].v, xR[par * 3 + dt], o[0][dt]);

            U4 f1[2];
            makefrags(s1, f1);
            {
                f32x16 nsv = {};
                #pragma unroll
                for (int kk = 0; kk < 5; ++kk) nsv = mfma_f16(kR[kk], aQ[1][kk], nsv);
                s1 = nsv;
            }
            #pragma unroll
            for (int par = 0; par < 2; ++par)
                #pragma unroll
                for (int dt = 0; dt < 3; ++dt)
                    o[1][dt] = mfma_bf16(f1[par].v, xR[par * 3 + dt], o[1][dt]);
        }
        __syncthreads();   // chunk c reads done; chunk c+1 staging landed
    }

    // epilogue: bf16 partials [q][NS][68]; col 66 = denominator
    #pragma unroll
    for (int qt = 0; qt < 2; ++qt)
        #pragma unroll
        for (int dt = 0; dt < 3; ++dt)
            #pragma unroll
            for (int r = 0; r < 16; ++r) {
                int row = (r & 3) + 8 * (r >> 2) + 4 * h;
                int q = qbase + qt * 32 + row;
                int d = dt * 32 + l31;
                if (d < DIM + 1)
                    Part[((long)q * NS + ns) * PARTP + d] = (__bf16)o[qt][dt][r];
            }
}

// ---------------------------------------------------------------------------
// Combine v2 (R25): out[q][d] = sum_s Part[q][s][d] / sum_s Part[q][s][66].
// One wave per 2 q (grid 1024 x 256 thr = 8 q/block). Lane j (j=lane&31)
// accumulates the u32 bf16-pair (d=2j, 2j+1); lanes j<2 also take pairs 32+j
// (d64..67; pair 33 low = denominator, high = pad, accumulated but unused).
// Denominator broadcast via shfl from lane (qq*32+1). Same per-element
// summation order and final division as v1 -> identical numerics.
// ---------------------------------------------------------------------------
__global__ __launch_bounds__(256) void combine_kernel(
    const unsigned short* __restrict__ Part_u, float* __restrict__ out) {
    const int tid = threadIdx.x;
    const int lane = tid & 63, wave = tid >> 6;
    const int j = lane & 31;
    const long q = (long)blockIdx.x * 8 + wave * 2 + (lane >> 5);
    // Part as u32 pairs: 544 u32 per q (NS*PARTP/2), 34 u32 per s-row
    const unsigned* base = (const unsigned*)Part_u + q * (NS * PARTP / 2);

    float nlo = 0.f, nhi = 0.f;     // pair j: d = 2j, 2j+1
    float elo = 0.f, ehi = 0.f;     // lanes j<2: pair 32+j (d64..67)
    #pragma unroll 4
    for (int s = 0; s < NS; ++s) {
        unsigned u = base[s * (PARTP / 2) + j];
        nlo += bf16lo(u); nhi += bf16hi(u);
        if (j < 2) {
            unsigned ue = base[s * (PARTP / 2) + 32 + j];
            elo += bf16lo(ue); ehi += bf16hi(ue);
        }
    }
    // denominator = pair-33 low half, held by lane (qq*32 + 1)
    float den = __shfl(elo, (lane & 32) + 1);

    float* op = out + q * DIM;
    op[2 * j]     = nlo / den;
    op[2 * j + 1] = nhi / den;
    if (j == 0) {                   // pair 32: d = 64, 65
        op[64] = elo / den;
        op[65] = ehi / den;
    }
}

// ---------------------------------------------------------------------------
// Workspace: Qh @0 (1,310,720 B) ; Af @1,310,720 (10,485,760 B) ;
//            Xf @11,796,480 (12,582,912 B) ; Part @24,379,392 (17,825,792 B)
// ---------------------------------------------------------------------------
extern "C" void kernel_launch(void* const* d_in, const int* in_sizes, int n_in,
                              void* d_out, int out_size, void* d_ws, size_t ws_size,
                              hipStream_t stream) {
    const float* x     = (const float*)d_in[0];
    const float* query = (const float*)d_in[1];
    const float* Wk    = (const float*)d_in[2];
    float* out = (float*)d_out;
    char* ws = (char*)d_ws;

    unsigned short* Qh   = (unsigned short*)(ws + 0);
    unsigned short* Af   = (unsigned short*)(ws + 1310720);
    unsigned short* Xf   = (unsigned short*)(ws + 11796480);
    unsigned short* Part = (unsigned short*)(ws + 24379392);

    prep_kernel<<<512 + NUM_Q / 128, 256, 0, stream>>>(x, query, Wk, Af, Xf, Qh);
    flash_kernel<<<(NUM_Q / 256) * NS, 256, 0, stream>>>(Qh, Af, Xf, Part);
    combine_kernel<<<NUM_Q / 8, 256, 0, stream>>>(Part, out);
}